// Round 3
// baseline (513.038 us; speedup 1.0000x reference)
//
#include <hip/hip_runtime.h>

// GND_61873298866219 — graph attention distance kernel
// Outputs (concat): attentions [E,4] floats, then f_src [E,4,16] floats.

typedef float fvec4 __attribute__((ext_vector_type(4)));  // native vec for nontemporal builtins

static __device__ __forceinline__ void nt_store4(const float4& v, float4* p) {
    fvec4 nv = { v.x, v.y, v.z, v.w };
    __builtin_nontemporal_store(nv, (fvec4*)p);
}

static __device__ __forceinline__ unsigned fmap_ord(float x) {
    // order-preserving float -> uint map (for atomicMin)
    unsigned u = __float_as_uint(x);
    return (u >> 31) ? ~u : (u | 0x80000000u);
}

__global__ void gnd_init(float* __restrict__ denom, double* __restrict__ gsum,
                         unsigned* __restrict__ gminu, int n)
{
    int i = blockIdx.x * blockDim.x + threadIdx.x;
    int stride = gridDim.x * blockDim.x;
    for (int j = i; j < n; j += stride) denom[j] = 0.0f;
    if (blockIdx.x == 0 && threadIdx.x < 4) {
        gsum[threadIdx.x] = 0.0;
        gminu[threadIdx.x] = 0xFFFFFFFFu;
    }
}

__global__ __launch_bounds__(256) void gnd_pass1(
    const float4* __restrict__ nodes4,     // [N*16] float4 (N nodes x 64 floats)
    const int* __restrict__ trgA,          // [E]
    const int* __restrict__ srcA,          // [E]
    const float4* __restrict__ w_edge4,    // [16]
    const float4* __restrict__ w_dist4,    // [16]
    float4* __restrict__ out_fsrc4,        // [E*16]
    float* __restrict__ ed,                // [E*4]
    double* __restrict__ gsum,             // [4]
    unsigned* __restrict__ gminu,          // [4]
    int E)
{
    const int lane = threadIdx.x & 63;
    const int q = lane & 15;               // float4 index within node (0..15)
    const int h = (lane >> 2) & 3;         // head for this lane's float4
    const float4 wE = w_edge4[q];
    const float4 wD = w_dist4[q];

    double sumAcc = 0.0;
    float  minAcc = 3.4e38f;

    const int gid  = blockIdx.x * blockDim.x + threadIdx.x;
    const int grp0 = gid >> 4;                          // edge-group id
    const int ngrp = (gridDim.x * blockDim.x) >> 4;     // total groups

    for (int base = grp0; base < E; base += 4 * ngrp) {
        int   eA[4], tA[4], sA[4];
        float4 fsA[4], ftA[4];
        #pragma unroll
        for (int k = 0; k < 4; ++k) {
            int e = base + k * ngrp;
            eA[k] = e;
            if (e < E) { tA[k] = trgA[e]; sA[k] = srcA[e]; }
        }
        #pragma unroll
        for (int k = 0; k < 4; ++k) {
            if (eA[k] < E) {
                fsA[k] = nodes4[sA[k] * 16 + q];
                ftA[k] = nodes4[tA[k] * 16 + q];
            }
        }
        #pragma unroll
        for (int k = 0; k < 4; ++k) {
            int e = eA[k];
            if (e >= E) break;
            float4 fs = fsA[k], ft = ftA[k];
            nt_store4(fs, &out_fsrc4[(size_t)e * 16 + q]);
            float ax = (ft.x - fs.x) * wE.x;
            float ay = (ft.y - fs.y) * wE.y;
            float az = (ft.z - fs.z) * wE.z;
            float aw = (ft.w - fs.w) * wE.w;
            float v = ax * ax * wD.x + ay * ay * wD.y + az * az * wD.z + aw * aw * wD.w;
            // reduce the 4 lanes of one head (adjacent lanes, uniform e per group)
            v += __shfl_xor(v, 1);
            v += __shfl_xor(v, 2);
            if ((lane & 3) == 0) {
                __builtin_nontemporal_store(v, &ed[(size_t)e * 4 + h]);
                sumAcc += (double)v;
                minAcc = fminf(minAcc, v);
            }
        }
    }
    // wave-level: combine the 4 contributing 16-lane groups (same h at lane^16, lane^32)
    sumAcc += __shfl_xor(sumAcc, 16);
    sumAcc += __shfl_xor(sumAcc, 32);
    minAcc = fminf(minAcc, __shfl_xor(minAcc, 16));
    minAcc = fminf(minAcc, __shfl_xor(minAcc, 32));

    __shared__ double sSum[4][4];  // [wave][head]
    __shared__ float  sMin[4][4];
    int wv = threadIdx.x >> 6;
    if (lane < 16 && (lane & 3) == 0) {
        sSum[wv][h] = sumAcc;
        sMin[wv][h] = minAcc;
    }
    __syncthreads();
    if (threadIdx.x < 4) {
        int hh = threadIdx.x;
        double s = sSum[0][hh] + sSum[1][hh] + sSum[2][hh] + sSum[3][hh];
        float  m = fminf(fminf(sMin[0][hh], sMin[1][hh]),
                         fminf(sMin[2][hh], sMin[3][hh]));
        atomicAdd(&gsum[hh], s);
        atomicMin(&gminu[hh], fmap_ord(m));
    }
}

__global__ void gnd_finalize(const double* __restrict__ gsum,
                             const unsigned* __restrict__ gminu,
                             float* __restrict__ consts, int E)
{
    if (threadIdx.x == 0 && blockIdx.x == 0) {
        float smax = -3.4e38f;
        for (int hh = 0; hh < 4; ++hh) {
            float mean = (float)(gsum[hh] / (double)E);
            unsigned m = gminu[hh];
            unsigned bits = (m >> 31) ? (m ^ 0x80000000u) : ~m;
            float mn = __uint_as_float(bits);
            float x = mn + mean;
            float lr = (x >= 0.f) ? x : 0.2f * x;
            smax = fmaxf(smax, -lr);
            consts[hh] = mean;
        }
        consts[4] = smax;
    }
}

static __device__ __forceinline__ float lrelu_exp(float x, float smax) {
    float lr = (x >= 0.f) ? x : 0.2f * x;
    return expf(-lr - smax);
}

__global__ __launch_bounds__(256) void gnd_pass2(
    const float4* __restrict__ ed4,        // [E] (4 heads per edge)
    const int* __restrict__ trgA,
    const float* __restrict__ consts,
    float* __restrict__ denom,             // [N*4], pre-zeroed
    int E)
{
    const float m0 = consts[0], m1 = consts[1], m2 = consts[2], m3 = consts[3];
    const float smax = consts[4];
    int gid = blockIdx.x * blockDim.x + threadIdx.x;
    int stride = gridDim.x * blockDim.x;
    for (int e = gid; e < E; e += stride) {
        float4 d = ed4[e];
        int t = trgA[e];
        atomicAdd(&denom[t * 4 + 0], lrelu_exp(d.x + m0, smax));
        atomicAdd(&denom[t * 4 + 1], lrelu_exp(d.y + m1, smax));
        atomicAdd(&denom[t * 4 + 2], lrelu_exp(d.z + m2, smax));
        atomicAdd(&denom[t * 4 + 3], lrelu_exp(d.w + m3, smax));
    }
}

__global__ __launch_bounds__(256) void gnd_pass3(
    const float4* __restrict__ ed4,
    const int* __restrict__ trgA,
    const float* __restrict__ consts,
    const float4* __restrict__ denom4,     // [N]
    float4* __restrict__ attOut4,          // [E]
    int E)
{
    const float m0 = consts[0], m1 = consts[1], m2 = consts[2], m3 = consts[3];
    const float smax = consts[4];
    int gid = blockIdx.x * blockDim.x + threadIdx.x;
    int stride = gridDim.x * blockDim.x;
    for (int e = gid; e < E; e += stride) {
        float4 d = ed4[e];
        int t = trgA[e];
        float4 den = denom4[t];
        float4 att;
        att.x = lrelu_exp(d.x + m0, smax) / (den.x + 1e-16f);
        att.y = lrelu_exp(d.y + m1, smax) / (den.y + 1e-16f);
        att.z = lrelu_exp(d.z + m2, smax) / (den.z + 1e-16f);
        att.w = lrelu_exp(d.w + m3, smax) / (den.w + 1e-16f);
        nt_store4(att, &attOut4[e]);
    }
}

extern "C" void kernel_launch(void* const* d_in, const int* in_sizes, int n_in,
                              void* d_out, int out_size, void* d_ws, size_t ws_size,
                              hipStream_t stream)
{
    const float* nodes  = (const float*)d_in[0];   // [N,4,16]
    const int*   ei     = (const int*)d_in[1];     // [2,E]
    const float* w_edge = (const float*)d_in[2];   // [1,4,16]
    const float* w_dist = (const float*)d_in[3];   // [1,4,16]

    const int N = in_sizes[0] / 64;
    const int E = in_sizes[1] / 2;
    const int* trgA = ei;          // edge_index[0]
    const int* srcA = ei + E;      // edge_index[1]

    float*  out_att   = (float*)d_out;                               // [E*4]
    float4* out_fsrc4 = (float4*)((float*)d_out + (size_t)E * 4);    // [E*16] float4

    // workspace layout (all 16B-aligned)
    float*    ed     = (float*)d_ws;                       // E*4 floats
    float*    denom  = ed + (size_t)E * 4;                 // N*4 floats
    double*   gsum   = (double*)(denom + (size_t)N * 4);   // 4 doubles
    unsigned* gminu  = (unsigned*)(gsum + 4);              // 4 uints
    float*    consts = (float*)(gminu + 4);                // mean[4], smax

    gnd_init<<<256, 256, 0, stream>>>(denom, gsum, gminu, N * 4);

    gnd_pass1<<<2048, 256, 0, stream>>>((const float4*)nodes, trgA, srcA,
                                        (const float4*)w_edge, (const float4*)w_dist,
                                        out_fsrc4, ed, gsum, gminu, E);
    gnd_finalize<<<1, 64, 0, stream>>>(gsum, gminu, consts, E);

    gnd_pass2<<<2048, 256, 0, stream>>>((const float4*)ed, trgA, consts, denom, E);
    gnd_pass3<<<2048, 256, 0, stream>>>((const float4*)ed, trgA, consts,
                                        (const float4*)denom, (float4*)out_att, E);
}

// Round 4
// 276.738 us; speedup vs baseline: 1.8539x; 1.8539x over previous
//
#include <hip/hip_runtime.h>

// GND_61873298866219 — graph attention distance kernel
// Outputs (concat): attentions [E,4] floats, then f_src [E,4,16] floats.

typedef float fvec4 __attribute__((ext_vector_type(4)));  // native vec for nontemporal builtins

static __device__ __forceinline__ void nt_store4(const float4& v, float4* p) {
    fvec4 nv = { v.x, v.y, v.z, v.w };
    __builtin_nontemporal_store(nv, (fvec4*)p);
}

static __device__ __forceinline__ unsigned fmap_ord(float x) {
    // order-preserving float -> uint map (for atomicMin)
    unsigned u = __float_as_uint(x);
    return (u >> 31) ? ~u : (u | 0x80000000u);
}

__global__ void gnd_init(float* __restrict__ denom, double* __restrict__ gsum,
                         unsigned* __restrict__ gminu, int n)
{
    int i = blockIdx.x * blockDim.x + threadIdx.x;
    int stride = gridDim.x * blockDim.x;
    for (int j = i; j < n; j += stride) denom[j] = 0.0f;
    if (blockIdx.x == 0 && threadIdx.x < 4) {
        gsum[threadIdx.x] = 0.0;
        gminu[threadIdx.x] = 0xFFFFFFFFu;
    }
}

__global__ __launch_bounds__(256) void gnd_pass1(
    const float4* __restrict__ nodes4,     // [N*16] float4 (N nodes x 64 floats)
    const int* __restrict__ trgA,          // [E]
    const int* __restrict__ srcA,          // [E]
    const float4* __restrict__ w_edge4,    // [16]
    const float4* __restrict__ w_dist4,    // [16]
    float4* __restrict__ out_fsrc4,        // [E*16]
    float* __restrict__ ed,                // [E*4]
    double* __restrict__ gsum,             // [4]
    unsigned* __restrict__ gminu,          // [4]
    int E)
{
    const int lane = threadIdx.x & 63;
    const int q = lane & 15;               // float4 index within node (0..15)
    const int h = (lane >> 2) & 3;         // head for this lane's float4
    const float4 wE = w_edge4[q];
    const float4 wD = w_dist4[q];

    double sumAcc = 0.0;
    float  minAcc = 3.4e38f;

    const int gid  = blockIdx.x * blockDim.x + threadIdx.x;
    const int grp0 = gid >> 4;                          // edge-group id
    const int ngrp = (gridDim.x * blockDim.x) >> 4;     // total groups

    for (int base = grp0; base < E; base += 4 * ngrp) {
        int   eA[4], tA[4], sA[4];
        float4 fsA[4], ftA[4];
        #pragma unroll
        for (int k = 0; k < 4; ++k) {
            int e = base + k * ngrp;
            eA[k] = e;
            if (e < E) { tA[k] = trgA[e]; sA[k] = srcA[e]; }
        }
        #pragma unroll
        for (int k = 0; k < 4; ++k) {
            if (eA[k] < E) {
                fsA[k] = nodes4[sA[k] * 16 + q];
                ftA[k] = nodes4[tA[k] * 16 + q];
            }
        }
        #pragma unroll
        for (int k = 0; k < 4; ++k) {
            int e = eA[k];
            if (e >= E) break;
            float4 fs = fsA[k], ft = ftA[k];
            nt_store4(fs, &out_fsrc4[(size_t)e * 16 + q]);
            float ax = (ft.x - fs.x) * wE.x;
            float ay = (ft.y - fs.y) * wE.y;
            float az = (ft.z - fs.z) * wE.z;
            float aw = (ft.w - fs.w) * wE.w;
            float v = ax * ax * wD.x + ay * ay * wD.y + az * az * wD.z + aw * aw * wD.w;
            // reduce the 4 lanes of one head (adjacent lanes, uniform e per group)
            v += __shfl_xor(v, 1);
            v += __shfl_xor(v, 2);
            if ((lane & 3) == 0) {
                __builtin_nontemporal_store(v, &ed[(size_t)e * 4 + h]);
                sumAcc += (double)v;
                minAcc = fminf(minAcc, v);
            }
        }
    }
    // wave-level: combine the 4 contributing 16-lane groups (same h at lane^16, lane^32)
    sumAcc += __shfl_xor(sumAcc, 16);
    sumAcc += __shfl_xor(sumAcc, 32);
    minAcc = fminf(minAcc, __shfl_xor(minAcc, 16));
    minAcc = fminf(minAcc, __shfl_xor(minAcc, 32));

    __shared__ double sSum[4][4];  // [wave][head]
    __shared__ float  sMin[4][4];
    int wv = threadIdx.x >> 6;
    if (lane < 16 && (lane & 3) == 0) {
        sSum[wv][h] = sumAcc;
        sMin[wv][h] = minAcc;
    }
    __syncthreads();
    if (threadIdx.x < 4) {
        int hh = threadIdx.x;
        double s = sSum[0][hh] + sSum[1][hh] + sSum[2][hh] + sSum[3][hh];
        float  m = fminf(fminf(sMin[0][hh], sMin[1][hh]),
                         fminf(sMin[2][hh], sMin[3][hh]));
        atomicAdd(&gsum[hh], s);
        atomicMin(&gminu[hh], fmap_ord(m));
    }
}

__global__ void gnd_finalize(const double* __restrict__ gsum,
                             const unsigned* __restrict__ gminu,
                             float* __restrict__ consts, int E)
{
    if (threadIdx.x == 0 && blockIdx.x == 0) {
        float smax = -3.4e38f;
        for (int hh = 0; hh < 4; ++hh) {
            float mean = (float)(gsum[hh] / (double)E);
            unsigned m = gminu[hh];
            unsigned bits = (m >> 31) ? (m ^ 0x80000000u) : ~m;
            float mn = __uint_as_float(bits);
            float x = mn + mean;
            float lr = (x >= 0.f) ? x : 0.2f * x;
            smax = fmaxf(smax, -lr);
            consts[hh] = mean;
        }
        consts[4] = smax;
    }
}

static __device__ __forceinline__ float lrelu_exp(float x, float smax) {
    float lr = (x >= 0.f) ? x : 0.2f * x;
    return expf(-lr - smax);
}

static __device__ __forceinline__ float head_mean(float m0, float m1, float m2, float m3, int hh) {
    float a = (hh & 1) ? m1 : m0;
    float b = (hh & 1) ? m3 : m2;
    return (hh & 2) ? b : a;
}

// per-(edge,head) mapping: adjacent lanes -> same edge, 4 consecutive denom
// addresses (one 16B sector per edge) — critical for atomic line-coalescing.
__global__ __launch_bounds__(256) void gnd_pass2(
    const float* __restrict__ ed,          // [E*4]
    const int* __restrict__ trgA,
    const float* __restrict__ consts,
    float* __restrict__ denom,             // [N*4], pre-zeroed
    int total)                             // E*4
{
    const float m0 = consts[0], m1 = consts[1], m2 = consts[2], m3 = consts[3];
    const float smax = consts[4];
    int gid = blockIdx.x * blockDim.x + threadIdx.x;
    int stride = gridDim.x * blockDim.x;
    for (int i = gid; i < total; i += stride) {
        int e = i >> 2, hh = i & 3;
        float x = ed[i] + head_mean(m0, m1, m2, m3, hh);
        atomicAdd(&denom[trgA[e] * 4 + hh], lrelu_exp(x, smax));
    }
}

__global__ __launch_bounds__(256) void gnd_pass3(
    const float4* __restrict__ ed4,
    const int* __restrict__ trgA,
    const float* __restrict__ consts,
    const float4* __restrict__ denom4,     // [N]
    float4* __restrict__ attOut4,          // [E]
    int E)
{
    const float m0 = consts[0], m1 = consts[1], m2 = consts[2], m3 = consts[3];
    const float smax = consts[4];
    int gid = blockIdx.x * blockDim.x + threadIdx.x;
    int stride = gridDim.x * blockDim.x;
    for (int e = gid; e < E; e += stride) {
        float4 d = ed4[e];
        int t = trgA[e];
        float4 den = denom4[t];
        float4 att;
        att.x = lrelu_exp(d.x + m0, smax) / (den.x + 1e-16f);
        att.y = lrelu_exp(d.y + m1, smax) / (den.y + 1e-16f);
        att.z = lrelu_exp(d.z + m2, smax) / (den.z + 1e-16f);
        att.w = lrelu_exp(d.w + m3, smax) / (den.w + 1e-16f);
        nt_store4(att, &attOut4[e]);
    }
}

extern "C" void kernel_launch(void* const* d_in, const int* in_sizes, int n_in,
                              void* d_out, int out_size, void* d_ws, size_t ws_size,
                              hipStream_t stream)
{
    const float* nodes  = (const float*)d_in[0];   // [N,4,16]
    const int*   ei     = (const int*)d_in[1];     // [2,E]
    const float* w_edge = (const float*)d_in[2];   // [1,4,16]
    const float* w_dist = (const float*)d_in[3];   // [1,4,16]

    const int N = in_sizes[0] / 64;
    const int E = in_sizes[1] / 2;
    const int* trgA = ei;          // edge_index[0]
    const int* srcA = ei + E;      // edge_index[1]

    float*  out_att   = (float*)d_out;                               // [E*4]
    float4* out_fsrc4 = (float4*)((float*)d_out + (size_t)E * 4);    // [E*16] float4

    // workspace layout (all 16B-aligned)
    float*    ed     = (float*)d_ws;                       // E*4 floats
    float*    denom  = ed + (size_t)E * 4;                 // N*4 floats
    double*   gsum   = (double*)(denom + (size_t)N * 4);   // 4 doubles
    unsigned* gminu  = (unsigned*)(gsum + 4);              // 4 uints
    float*    consts = (float*)(gminu + 4);                // mean[4], smax

    gnd_init<<<256, 256, 0, stream>>>(denom, gsum, gminu, N * 4);

    gnd_pass1<<<2048, 256, 0, stream>>>((const float4*)nodes, trgA, srcA,
                                        (const float4*)w_edge, (const float4*)w_dist,
                                        out_fsrc4, ed, gsum, gminu, E);
    gnd_finalize<<<1, 64, 0, stream>>>(gsum, gminu, consts, E);

    gnd_pass2<<<2048, 256, 0, stream>>>(ed, trgA, consts, denom, E * 4);
    gnd_pass3<<<2048, 256, 0, stream>>>((const float4*)ed, trgA, consts,
                                        (const float4*)denom, (float4*)out_att, E);
}